// Round 7
// baseline (227.496 us; speedup 1.0000x reference)
//
#include <hip/hip_runtime.h>
#include <hip/hip_bf16.h>

// KAN layer: out = einsum('bik,jik->bj', rbf(x), W) + silu(x)@Wb^T, then LN.
// GEMM view: C[4096,512] = A[4096,8704] * B[512,8704]^T in bf16 MFMA.
//
// R7: BARRIER-FREE GEMM. R2/R3/R6 all plateaued at ~56-58µs because
// __syncthreads() emits s_waitcnt vmcnt(0) — draining ALL vmem (including
// "barrier-free" B loads and prefetch DMAs) every iter; 16 waves/CU convoy
// behind ~500cyc LLC latency each iter (wall 4.1k cyc vs 1.24k MFMA demand).
// Fix: no LDS at all. A row-major fragment (16 rows x 64B at KT-stride) is
// exactly 16 fully-consumed cache lines == same traffic as a contiguous slab,
// so A and B frags load directly from global via one dwordx4 gather each.
// No barriers => compiler pipelines loads with fine vmcnt; waves independent.
//
// d_ws layout (113,770,496 B):
//   A  bf16 [4096][8704]   @ 0        (71,303,168 B)  row-major [basis|silu]
//   Bm bf16 [512][8704]    @ 71303168 ( 8,912,896 B)  row-major [W|Wb]
//   Cp bf16 [8][4096][512] @ 80216064 (33,554,432 B)  split-K partials

typedef __bf16 bf16x8 __attribute__((ext_vector_type(8)));
typedef __bf16 bf16x4 __attribute__((ext_vector_type(4)));
typedef float  f32x4  __attribute__((ext_vector_type(4)));

#define KT 8704
#define SPLITS 8
#define NIT 34                 // 1088 K per z-slice / BK=32
#define CPE (4096 * 512)

__device__ __forceinline__ float fsilu(float t) {
    return t * __builtin_amdgcn_rcpf(1.0f + __expf(-t));
}

// ---- kernel 1: A = [rbf basis | silu(x)], Bm = [W | Wb], both bf16 --------
// (R2's proven coalesced version, verbatim)
// centers linspace(-2,2,16), h = 4/15 => z_k = 3.75x + 7.5 - k
__global__ void prep_AB(const float* __restrict__ x, const float* __restrict__ W,
                        const float* __restrict__ Wb, __bf16* __restrict__ A,
                        __bf16* __restrict__ B) {
    if (blockIdx.x < 8192) {                     // A-part: 1 thread per x elem
        int t = blockIdx.x * 256 + threadIdx.x;  // 0 .. 4096*512
        int b = t >> 9;
        int i = t & 511;
        float xv = x[t];
        float zb = 3.75f * xv + 7.5f;
        bf16x8 lo, hi;
#pragma unroll
        for (int k = 0; k < 8; ++k) { float z = zb - (float)k; lo[k]   = (__bf16)__expf(-z * z); }
#pragma unroll
        for (int k = 8; k < 16; ++k){ float z = zb - (float)k; hi[k-8] = (__bf16)__expf(-z * z); }
        size_t base = (size_t)b * KT + (size_t)i * 16;
        *(bf16x8*)(A + base)     = lo;
        *(bf16x8*)(A + base + 8) = hi;
        A[(size_t)b * KT + 8192 + i] = (__bf16)fsilu(xv);
    } else {                                     // B-part: cast W|Wb, 4 elems/thread
        int t = (blockIdx.x - 8192) * 256 + threadIdx.x;  // 0 .. 512*2176
        int j = t / 2176;
        int c = (t - j * 2176) * 4;
        float4 v;
        if (c < 8192) v = *(const float4*)&W[(size_t)j * 8192 + c];
        else          v = *(const float4*)&Wb[(size_t)j * 512 + (c - 8192)];
        bf16x4 o;
        o[0] = (__bf16)v.x; o[1] = (__bf16)v.y; o[2] = (__bf16)v.z; o[3] = (__bf16)v.w;
        *(bf16x4*)&B[(size_t)j * KT + c] = o;
    }
}

// ---- kernel 2: split-K GEMM 128x128, fragments direct from global ---------
// Wave (wm,wn) owns a 64x64 subtile. Frag (mi,q): lane(q,r16) loads 16B at
// row (m0+wm*64+mi*16+r16), k = k0+it*32+q*8 — 16 cache lines per frag, all
// fully consumed (k0+it*32 is 64B-aligned). No LDS, no __syncthreads.
__global__ __launch_bounds__(256) void gemm_direct(const __bf16* __restrict__ A,
                                                   const __bf16* __restrict__ B,
                                                   __bf16* __restrict__ Cp) {
    const int tid  = threadIdx.x;
    const int wave = tid >> 6, lane = tid & 63;
    const int q    = lane >> 4, r16 = lane & 15;
    const int m0 = blockIdx.x * 128, n0 = blockIdx.y * 128;
    const int bz = blockIdx.z, k0 = bz * 1088;
    const int wm = wave & 1, wn = wave >> 1;

    const __bf16* aBase = A + (size_t)(m0 + wm * 64 + r16) * KT + k0 + q * 8;
    const __bf16* bBase = B + (size_t)(n0 + wn * 64 + r16) * KT + k0 + q * 8;

    f32x4 acc[4][4] = {};

#pragma unroll 2
    for (int it = 0; it < NIT; ++it) {
        const __bf16* ap = aBase + it * 32;
        const __bf16* bp = bBase + it * 32;
        bf16x8 af[4], bg[4];
#pragma unroll
        for (int mi = 0; mi < 4; ++mi) af[mi] = *(const bf16x8*)(ap + (size_t)(mi * 16) * KT);
#pragma unroll
        for (int ni = 0; ni < 4; ++ni) bg[ni] = *(const bf16x8*)(bp + (size_t)(ni * 16) * KT);
#pragma unroll
        for (int mi = 0; mi < 4; ++mi)
#pragma unroll
            for (int ni = 0; ni < 4; ++ni)
                acc[mi][ni] = __builtin_amdgcn_mfma_f32_16x16x32_bf16(
                    af[mi], bg[ni], acc[mi][ni], 0, 0, 0);
    }

    // epilogue: C/D layout col=lane&15, row=(lane>>4)*4+reg; bf16 partials
    __bf16* Cb = Cp + (size_t)bz * CPE;
#pragma unroll
    for (int mi = 0; mi < 4; ++mi) {
        const int row = m0 + wm * 64 + mi * 16 + q * 4;
#pragma unroll
        for (int ni = 0; ni < 4; ++ni) {
            const int col = n0 + wn * 64 + ni * 16 + r16;
#pragma unroll
            for (int r = 0; r < 4; ++r)
                Cb[(size_t)(row + r) * 512 + col] = (__bf16)acc[mi][ni][r];
        }
    }
}

// ---- kernel 3: sum 8 bf16 partials + LayerNorm, one wave per row ----------
__global__ void ln_kernel(const __bf16* __restrict__ Cp, const float* __restrict__ gamma,
                          const float* __restrict__ beta, float* __restrict__ out) {
    const int tid  = threadIdx.x;
    const int wave = tid >> 6, lane = tid & 63;
    const int row  = blockIdx.x * 4 + wave;
    const size_t base = (size_t)row * 512 + lane * 8;

    float v[8] = {};
    float s = 0.f, s2 = 0.f;
#pragma unroll
    for (int z = 0; z < SPLITS; ++z) {
        bf16x8 pv = *(const bf16x8*)(Cp + (size_t)z * CPE + base);
#pragma unroll
        for (int j = 0; j < 8; ++j) v[j] += (float)pv[j];
    }
#pragma unroll
    for (int j = 0; j < 8; ++j) { s += v[j]; s2 += v[j] * v[j]; }
#pragma unroll
    for (int m = 32; m >= 1; m >>= 1) {
        s  += __shfl_xor(s, m);
        s2 += __shfl_xor(s2, m);
    }
    const float mean = s * (1.0f / 512.0f);
    const float var  = s2 * (1.0f / 512.0f) - mean * mean;
    const float rs   = rsqrtf(var + 1e-5f);
    float4 o0, o1;
    const float4 g0 = *(const float4*)&gamma[lane * 8];
    const float4 g1 = *(const float4*)&gamma[lane * 8 + 4];
    const float4 b0 = *(const float4*)&beta[lane * 8];
    const float4 b1 = *(const float4*)&beta[lane * 8 + 4];
    o0.x = (v[0] - mean) * rs * g0.x + b0.x;
    o0.y = (v[1] - mean) * rs * g0.y + b0.y;
    o0.z = (v[2] - mean) * rs * g0.z + b0.z;
    o0.w = (v[3] - mean) * rs * g0.w + b0.w;
    o1.x = (v[4] - mean) * rs * g1.x + b1.x;
    o1.y = (v[5] - mean) * rs * g1.y + b1.y;
    o1.z = (v[6] - mean) * rs * g1.z + b1.z;
    o1.w = (v[7] - mean) * rs * g1.w + b1.w;
    *(float4*)&out[base]     = o0;
    *(float4*)&out[base + 4] = o1;
}

extern "C" void kernel_launch(void* const* d_in, const int* in_sizes, int n_in,
                              void* d_out, int out_size, void* d_ws, size_t ws_size,
                              hipStream_t stream) {
    const float* x     = (const float*)d_in[0];
    const float* W     = (const float*)d_in[1];
    const float* Wb    = (const float*)d_in[2];
    const float* gamma = (const float*)d_in[3];
    const float* beta  = (const float*)d_in[4];
    float* out = (float*)d_out;

    char* ws = (char*)d_ws;
    __bf16* A  = (__bf16*)ws;                 // 71,303,168 B
    __bf16* Bm = (__bf16*)(ws + 71303168);    //  8,912,896 B
    __bf16* Cp = (__bf16*)(ws + 80216064);    // 33,554,432 B

    prep_AB<<<8192 + 4352, 256, 0, stream>>>(x, W, Wb, A, Bm);
    dim3 g(32, 4, SPLITS);
    gemm_direct<<<g, 256, 0, stream>>>(A, Bm, Cp);
    ln_kernel<<<1024, 256, 0, stream>>>(Cp, gamma, beta, out);
}

// Round 8
// 190.170 us; speedup vs baseline: 1.1963x; 1.1963x over previous
//
#include <hip/hip_runtime.h>
#include <hip/hip_bf16.h>

// KAN layer: out = einsum('bik,jik->bj', rbf(x), W) + silu(x)@Wb^T, then LN.
// GEMM view: C[4096,512] = A[4096,8704] * B[512,8704]^T in bf16 MFMA.
//
// R8: barrier-free gemm with BOTH operands in k-slab layout.
// Evidence: R2/R3/R6 (any K-loop barrier) pin at ~56-58µs (vmcnt(0) convoy);
// R7 (barrier-free, row-major gathers) regressed 2.4x — address-divergent
// 16-line gathers serialize the TA/L1 pipe. Fix: A2[k/32][row][k%32] and
// B2[k/32][col][k%32]: an MFMA fragment (lane addr r16*32+q*8) is then ONE
// fully-coalesced contiguous 1KB/wave dwordx4. No LDS, no __syncthreads in
// the gemm; waves independent; compiler pipelines with fine-grained vmcnt.
// Prep uses an LDS transpose (x reads coalesced, A2 writes coalesced,
// 513-pad => conflict-free) — fixing R5's strided-read prep failure.
//
// d_ws layout (113,770,496 B):
//   A2 bf16 [272][4096][32] @ 0        (71,303,168 B)  [basis k<8192 | silu]
//   B2 bf16 [272][512][32]  @ 71303168 ( 8,912,896 B)  [W | Wb]
//   Cp bf16 [8][4096][512]  @ 80216064 (33,554,432 B)  split-K partials

typedef __bf16 bf16x8 __attribute__((ext_vector_type(8)));
typedef __bf16 bf16x4 __attribute__((ext_vector_type(4)));
typedef float  f32x4  __attribute__((ext_vector_type(4)));

#define SPLITS 8
#define NIT 34                 // 1088 K per z-slice / 32
#define CPE (4096 * 512)
#define ASLAB (4096 * 32)      // A2 slab stride (elements)
#define BSLAB (512 * 32)       // B2 slab stride (elements)

__device__ __forceinline__ float fsilu(float t) {
    return t * __builtin_amdgcn_rcpf(1.0f + __expf(-t));
}

// ---- kernel 1: prep. blocks 0..255: A2 via LDS transpose; rest: B2 --------
// slab s (<256) covers k=32s..32s+31  <=>  i=2s,2s+1, kk=(i&1)*16+kappa.
// slabs 256..271 = silu: kk = i&31, slab = 256+(i>>5).
// centers linspace(-2,2,16), h=4/15 => z_k = 3.75x + 7.5 - k
__global__ void prep_all(const float* __restrict__ x, const float* __restrict__ W,
                         const float* __restrict__ Wb, __bf16* __restrict__ A2,
                         __bf16* __restrict__ B2) {
    __shared__ float xs[16][513];              // +1 pad: conflict-free col reads
    const int blk = blockIdx.x, tid = threadIdx.x;
    if (blk < 256) {                           // A2: 16 b-rows per block
        const int b0 = blk * 16;
        // load 16x512 x-tile, coalesced (8 float4 per thread)
#pragma unroll
        for (int r = 0; r < 8; ++r) {
            int f = r * 1024 + tid * 4;
            int row = f >> 9, col = f & 511;
            float4 v = *(const float4*)&x[(size_t)(b0 + row) * 512 + col];
            xs[row][col] = v.x; xs[row][col + 1] = v.y;
            xs[row][col + 2] = v.z; xs[row][col + 3] = v.w;
        }
        __syncthreads();
        const int b = tid & 15, ipb = tid >> 4;
        // basis: 16 chunks per thread; lanes 0..15 (b=0..15, same ip) write
        // 16x64B = 1KB contiguous per quarter-wave.
#pragma unroll
        for (int c = 0; c < 16; ++c) {
            const int ip = ipb * 16 + c;
            float x0 = xs[b][2 * ip], x1 = xs[b][2 * ip + 1];
            float zb0 = 3.75f * x0 + 7.5f, zb1 = 3.75f * x1 + 7.5f;
            bf16x8 v0, v1, v2, v3;
#pragma unroll
            for (int j = 0; j < 8; ++j) {
                float d0 = zb0 - (float)j;       v0[j] = (__bf16)__expf(-d0 * d0);
                float d1 = zb0 - (float)(j + 8); v1[j] = (__bf16)__expf(-d1 * d1);
                float d2 = zb1 - (float)j;       v2[j] = (__bf16)__expf(-d2 * d2);
                float d3 = zb1 - (float)(j + 8); v3[j] = (__bf16)__expf(-d3 * d3);
            }
            __bf16* p = A2 + ((size_t)ip * 4096 + b0 + b) * 32;
            *(bf16x8*)(p)      = v0;
            *(bf16x8*)(p + 8)  = v1;
            *(bf16x8*)(p + 16) = v2;
            *(bf16x8*)(p + 24) = v3;
        }
        // silu: 1 chunk (32 cols) per thread; slab 256+(i0>>5)
        {
            const int i0 = ipb * 32;
            bf16x8 s0, s1, s2, s3;
#pragma unroll
            for (int e = 0; e < 8; ++e) {
                s0[e] = (__bf16)fsilu(xs[b][i0 + e]);
                s1[e] = (__bf16)fsilu(xs[b][i0 + 8 + e]);
                s2[e] = (__bf16)fsilu(xs[b][i0 + 16 + e]);
                s3[e] = (__bf16)fsilu(xs[b][i0 + 24 + e]);
            }
            __bf16* p = A2 + ((size_t)(256 + ipb) * 4096 + b0 + b) * 32;
            *(bf16x8*)(p)      = s0;
            *(bf16x8*)(p + 8)  = s1;
            *(bf16x8*)(p + 16) = s2;
            *(bf16x8*)(p + 24) = s3;
        }
    } else {                                   // B2: 4 elems per thread
        int t = (blk - 256) * 256 + tid;       // 0 .. 512*2176
        int j = t / 2176;
        int c = (t - j * 2176) * 4;            // global k
        float4 v;
        if (c < 8192) v = *(const float4*)&W[(size_t)j * 8192 + c];
        else          v = *(const float4*)&Wb[(size_t)j * 512 + (c - 8192)];
        bf16x4 o;
        o[0] = (__bf16)v.x; o[1] = (__bf16)v.y; o[2] = (__bf16)v.z; o[3] = (__bf16)v.w;
        *(bf16x4*)(B2 + ((size_t)(c >> 5) * 512 + j) * 32 + (c & 31)) = o;
    }
}

// ---- kernel 2: split-K GEMM 128x128, barrier-free, slab-coalesced frags ---
// Frag load: 64 lanes tile [base, base+1024B) contiguously (r16*32+q*8 elems)
// -> one coalesced global_load_dwordx4 per frag, no LDS, no syncthreads.
__global__ __launch_bounds__(256) void gemm_slab(const __bf16* __restrict__ A2,
                                                 const __bf16* __restrict__ B2,
                                                 __bf16* __restrict__ Cp) {
    const int tid  = threadIdx.x;
    const int wave = tid >> 6, lane = tid & 63;
    const int q    = lane >> 4, r16 = lane & 15;
    const int m0 = blockIdx.x * 128, n0 = blockIdx.y * 128;
    const int bz = blockIdx.z, slab0 = bz * NIT;
    const int wm = wave & 1, wn = wave >> 1;

    const __bf16* aBase = A2 + (size_t)slab0 * ASLAB
                        + (size_t)(m0 + wm * 64 + r16) * 32 + q * 8;
    const __bf16* bBase = B2 + (size_t)slab0 * BSLAB
                        + (size_t)(n0 + wn * 64 + r16) * 32 + q * 8;

    f32x4 acc[4][4] = {};

#pragma unroll 2
    for (int it = 0; it < NIT; ++it) {
        const __bf16* ap = aBase + (size_t)it * ASLAB;
        const __bf16* bp = bBase + (size_t)it * BSLAB;
        bf16x8 af[4], bg[4];
#pragma unroll
        for (int mi = 0; mi < 4; ++mi) af[mi] = *(const bf16x8*)(ap + mi * 512);
#pragma unroll
        for (int ni = 0; ni < 4; ++ni) bg[ni] = *(const bf16x8*)(bp + ni * 512);
#pragma unroll
        for (int mi = 0; mi < 4; ++mi)
#pragma unroll
            for (int ni = 0; ni < 4; ++ni)
                acc[mi][ni] = __builtin_amdgcn_mfma_f32_16x16x32_bf16(
                    af[mi], bg[ni], acc[mi][ni], 0, 0, 0);
    }

    // epilogue: C/D layout col=lane&15, row=(lane>>4)*4+reg; bf16 partials
    __bf16* Cb = Cp + (size_t)bz * CPE;
#pragma unroll
    for (int mi = 0; mi < 4; ++mi) {
        const int row = m0 + wm * 64 + mi * 16 + q * 4;
#pragma unroll
        for (int ni = 0; ni < 4; ++ni) {
            const int col = n0 + wn * 64 + ni * 16 + r16;
#pragma unroll
            for (int r = 0; r < 4; ++r)
                Cb[(size_t)(row + r) * 512 + col] = (__bf16)acc[mi][ni][r];
        }
    }
}

// ---- kernel 3: sum 8 bf16 partials + LayerNorm, one wave per row ----------
__global__ void ln_kernel(const __bf16* __restrict__ Cp, const float* __restrict__ gamma,
                          const float* __restrict__ beta, float* __restrict__ out) {
    const int tid  = threadIdx.x;
    const int wave = tid >> 6, lane = tid & 63;
    const int row  = blockIdx.x * 4 + wave;
    const size_t base = (size_t)row * 512 + lane * 8;

    float v[8] = {};
    float s = 0.f, s2 = 0.f;
#pragma unroll
    for (int z = 0; z < SPLITS; ++z) {
        bf16x8 pv = *(const bf16x8*)(Cp + (size_t)z * CPE + base);
#pragma unroll
        for (int j = 0; j < 8; ++j) v[j] += (float)pv[j];
    }
#pragma unroll
    for (int j = 0; j < 8; ++j) { s += v[j]; s2 += v[j] * v[j]; }
#pragma unroll
    for (int m = 32; m >= 1; m >>= 1) {
        s  += __shfl_xor(s, m);
        s2 += __shfl_xor(s2, m);
    }
    const float mean = s * (1.0f / 512.0f);
    const float var  = s2 * (1.0f / 512.0f) - mean * mean;
    const float rs   = rsqrtf(var + 1e-5f);
    float4 o0, o1;
    const float4 g0 = *(const float4*)&gamma[lane * 8];
    const float4 g1 = *(const float4*)&gamma[lane * 8 + 4];
    const float4 b0 = *(const float4*)&beta[lane * 8];
    const float4 b1 = *(const float4*)&beta[lane * 8 + 4];
    o0.x = (v[0] - mean) * rs * g0.x + b0.x;
    o0.y = (v[1] - mean) * rs * g0.y + b0.y;
    o0.z = (v[2] - mean) * rs * g0.z + b0.z;
    o0.w = (v[3] - mean) * rs * g0.w + b0.w;
    o1.x = (v[4] - mean) * rs * g1.x + b1.x;
    o1.y = (v[5] - mean) * rs * g1.y + b1.y;
    o1.z = (v[6] - mean) * rs * g1.z + b1.z;
    o1.w = (v[7] - mean) * rs * g1.w + b1.w;
    *(float4*)&out[base]     = o0;
    *(float4*)&out[base + 4] = o1;
}

extern "C" void kernel_launch(void* const* d_in, const int* in_sizes, int n_in,
                              void* d_out, int out_size, void* d_ws, size_t ws_size,
                              hipStream_t stream) {
    const float* x     = (const float*)d_in[0];
    const float* W     = (const float*)d_in[1];
    const float* Wb    = (const float*)d_in[2];
    const float* gamma = (const float*)d_in[3];
    const float* beta  = (const float*)d_in[4];
    float* out = (float*)d_out;

    char* ws = (char*)d_ws;
    __bf16* A2 = (__bf16*)ws;                 // 71,303,168 B
    __bf16* B2 = (__bf16*)(ws + 71303168);    //  8,912,896 B
    __bf16* Cp = (__bf16*)(ws + 80216064);    // 33,554,432 B

    prep_all<<<256 + 4352, 256, 0, stream>>>(x, W, Wb, A2, B2);
    dim3 g(32, 4, SPLITS);
    gemm_slab<<<g, 256, 0, stream>>>(A2, B2, Cp);
    ln_kernel<<<1024, 256, 0, stream>>>(Cp, gamma, beta, out);
}